// Round 3
// baseline (25515.759 us; speedup 1.0000x reference)
//
#include <hip/hip_runtime.h>
#include <math.h>

#define CTX 77
#define WIDTH 512
#define HEADS 8
#define DH 64
#define LAYERS 12
#define EMBED 1024
#define NTXT 128
#define PP 8
#define LPROMPT 16
#define EOTTOK 49407
#define BSEQ (PP*NTXT)          // 1024
#define ROWS (BSEQ*CTX)         // 78848

typedef unsigned short ushort_t;
typedef __attribute__((ext_vector_type(8))) short short8;
typedef __attribute__((ext_vector_type(4))) float floatx4;

__device__ __forceinline__ float b2f(ushort_t u){
  union { unsigned int i; float f; } x; x.i = ((unsigned int)u) << 16; return x.f;
}
__device__ __forceinline__ ushort_t f2b(float f){
  union { float f; unsigned int i; } x; x.f = f;
  unsigned int r = x.i + 0x7fffu + ((x.i >> 16) & 1u);
  return (ushort_t)(r >> 16);
}
__device__ __forceinline__ float wsum(float v){
  #pragma unroll
  for (int o = 32; o > 0; o >>= 1) v += __shfl_xor(v, o, 64);
  return v;
}
__device__ __forceinline__ float wmax(float v){
  #pragma unroll
  for (int o = 32; o > 0; o >>= 1) v = fmaxf(v, __shfl_xor(v, o, 64));
  return v;
}

// -------- pos_y: first EOT position per text row --------
__global__ void k_posy(const int* __restrict__ text, int* __restrict__ posy){
  int n = threadIdx.x;
  if (n < NTXT){
    int p = 0;
    for (int t = 0; t < CTX; ++t){ if (text[n*CTX + t] == EOTTOK){ p = t; break; } }
    posy[n] = p;
  }
}

// -------- embedding + prompt splice + pos_emb -> H --------
template<bool RF32>
__global__ __launch_bounds__(256) void k_embed(
    const int* __restrict__ text, const float* __restrict__ cprompt,
    const float* __restrict__ tok_emb, const float* __restrict__ pos_emb,
    const int* __restrict__ posy, void* __restrict__ Hp)
{
  long long idx = (long long)blockIdx.x * 256 + threadIdx.x;
  int d   = (int)(idx & 511);
  int row = (int)(idx >> 9);
  int t  = row % CTX;
  int pn = row / CTX;
  int n  = pn % NTXT;
  int p  = pn / NTXT;
  int py = posy[n];
  float v;
  if (t >= py && t < py + LPROMPT){
    int pidx = t - py;
    v = cprompt[(p*LPROMPT + pidx)*WIDTH + d];
  } else {
    int src = (t < py) ? t : (t - LPROMPT + 1);
    src = min(max(src, 0), CTX-1);
    int tok = text[n*CTX + src];
    v = tok_emb[(long long)tok*WIDTH + d];
  }
  v += pos_emb[t*WIDTH + d];
  if constexpr (RF32) ((float*)Hp)[idx] = v;
  else                ((ushort_t*)Hp)[idx] = f2b(v);
}

// -------- LayerNorm: H -> Y(bf16), one wave per 512-row --------
template<bool RF32>
__global__ __launch_bounds__(256) void k_ln(
    const void* __restrict__ Hp, const float* __restrict__ w,
    const float* __restrict__ b, ushort_t* __restrict__ Y, int nrows)
{
  int wid = threadIdx.x >> 6, lane = threadIdx.x & 63;
  int row = blockIdx.x * 4 + wid;
  if (row >= nrows) return;
  float v[8];
  if constexpr (RF32){
    const float* x = (const float*)Hp + (long long)row * WIDTH;
    #pragma unroll
    for (int i = 0; i < 8; ++i) v[i] = x[lane*8 + i];
  } else {
    const ushort_t* x = (const ushort_t*)Hp + (long long)row * WIDTH;
    int4 raw = *(const int4*)(x + lane*8);
    ushort_t* u = (ushort_t*)&raw;
    #pragma unroll
    for (int i = 0; i < 8; ++i) v[i] = b2f(u[i]);
  }
  float s = 0.f, ss = 0.f;
  #pragma unroll
  for (int i = 0; i < 8; ++i){ s += v[i]; ss += v[i]*v[i]; }
  s = wsum(s); ss = wsum(ss);
  float mean = s * (1.0f/WIDTH);
  float var  = ss * (1.0f/WIDTH) - mean*mean;
  float rs = rsqrtf(var + 1e-5f);
  ushort_t o[8];
  #pragma unroll
  for (int i = 0; i < 8; ++i){
    int d = lane*8 + i;
    o[i] = f2b((v[i]-mean)*rs*w[d] + b[d]);
  }
  *(int4*)(Y + (long long)row*WIDTH + lane*8) = *(int4*)o;
}

// -------- GEMM: C[M,N] = A[M,K](bf16) @ W[N,K]^T(fp32->bf16) + bias --------
// MODE 0: O=bf16(acc+bias)  MODE 1: O=bf16(gelu(acc+bias))  MODE 2: H += acc+bias
template<int MODE, bool RF32>
__global__ __launch_bounds__(256) void k_gemm(
    const ushort_t* __restrict__ A, const float* __restrict__ W,
    const float* __restrict__ bias, void* __restrict__ Hp,
    ushort_t* __restrict__ O, int K, int N)
{
  __shared__ ushort_t As[128*32];
  __shared__ ushort_t Bs[128*32];
  int tid  = threadIdx.x;
  int lane = tid & 63, wid = tid >> 6;
  int wm = wid >> 1, wn = wid & 1;
  long long m0 = (long long)blockIdx.y * 128;
  int n0 = blockIdx.x * 128;

  floatx4 acc[4][4];
  #pragma unroll
  for (int i = 0; i < 4; ++i)
    #pragma unroll
    for (int j = 0; j < 4; ++j){ floatx4 z = {0.f,0.f,0.f,0.f}; acc[i][j] = z; }

  int e0 = tid*8, e1 = (256+tid)*8;
  int r0 = e0 >> 5, c0 = e0 & 31;
  int r1 = e1 >> 5, c1 = e1 & 31;

  for (int k0 = 0; k0 < K; k0 += 32){
    int4 a0 = *(const int4*)(A + (m0 + r0)*K + k0 + c0);
    int4 a1 = *(const int4*)(A + (m0 + r1)*K + k0 + c1);
    const float* wp0 = W + (size_t)(n0 + r0)*K + k0 + c0;
    const float* wp1 = W + (size_t)(n0 + r1)*K + k0 + c1;
    float4 b0a = *(const float4*)(wp0);
    float4 b0b = *(const float4*)(wp0 + 4);
    float4 b1a = *(const float4*)(wp1);
    float4 b1b = *(const float4*)(wp1 + 4);
    ushort_t bw0[8], bw1[8];
    bw0[0]=f2b(b0a.x); bw0[1]=f2b(b0a.y); bw0[2]=f2b(b0a.z); bw0[3]=f2b(b0a.w);
    bw0[4]=f2b(b0b.x); bw0[5]=f2b(b0b.y); bw0[6]=f2b(b0b.z); bw0[7]=f2b(b0b.w);
    bw1[0]=f2b(b1a.x); bw1[1]=f2b(b1a.y); bw1[2]=f2b(b1a.z); bw1[3]=f2b(b1a.w);
    bw1[4]=f2b(b1b.x); bw1[5]=f2b(b1b.y); bw1[6]=f2b(b1b.z); bw1[7]=f2b(b1b.w);
    __syncthreads();
    *(int4*)(As + e0) = a0; *(int4*)(As + e1) = a1;
    *(int4*)(Bs + e0) = *(int4*)bw0; *(int4*)(Bs + e1) = *(int4*)bw1;
    __syncthreads();
    int quad = lane >> 4, r = lane & 15;
    short8 af[4], bf[4];
    #pragma unroll
    for (int i = 0; i < 4; ++i) af[i] = *(const short8*)(As + (wm*64 + i*16 + r)*32 + quad*8);
    #pragma unroll
    for (int j = 0; j < 4; ++j) bf[j] = *(const short8*)(Bs + (wn*64 + j*16 + r)*32 + quad*8);
    #pragma unroll
    for (int i = 0; i < 4; ++i)
      #pragma unroll
      for (int j = 0; j < 4; ++j)
        acc[i][j] = __builtin_amdgcn_mfma_f32_16x16x32_bf16(af[i], bf[j], acc[i][j], 0, 0, 0);
  }

  int quad = lane >> 4, cn = lane & 15;
  #pragma unroll
  for (int i = 0; i < 4; ++i){
    #pragma unroll
    for (int j = 0; j < 4; ++j){
      int gcol = n0 + wn*64 + j*16 + cn;
      float bv = bias[gcol];
      #pragma unroll
      for (int rg = 0; rg < 4; ++rg){
        long long grow = m0 + wm*64 + i*16 + quad*4 + rg;
        float v = acc[i][j][rg] + bv;
        if (MODE == 0){
          O[grow*N + gcol] = f2b(v);
        } else if (MODE == 1){
          float g = v / (1.0f + __expf(-1.702f*v));
          O[grow*N + gcol] = f2b(g);
        } else {
          long long idx = grow*N + gcol;
          if constexpr (RF32) ((float*)Hp)[idx] += v;
          else { ushort_t* hb = (ushort_t*)Hp; hb[idx] = f2b(b2f(hb[idx]) + v); }
        }
      }
    }
  }
}

// -------- causal attention per (seq, head); QKV[b,77,1536](bf16) -> Y[b,77,512](bf16) --------
__global__ __launch_bounds__(256) void k_attn(
    const ushort_t* __restrict__ QKV, ushort_t* __restrict__ Y)
{
  __shared__ float qL[CTX*65];
  __shared__ float kL[CTX*65];
  __shared__ float vL[CTX*65];
  __shared__ float pL[4][128];
  int b = blockIdx.x >> 3, h = blockIdx.x & 7;
  int tid = threadIdx.x;
  const ushort_t* base = QKV + (long long)b*CTX*1536 + h*64;
  for (int idx = tid; idx < CTX*64; idx += 256){
    int t = idx >> 6, d = idx & 63;
    const ushort_t* rp = base + (long long)t*1536 + d;
    qL[t*65+d] = b2f(rp[0]);
    kL[t*65+d] = b2f(rp[512]);
    vL[t*65+d] = b2f(rp[1024]);
  }
  __syncthreads();
  int wid = tid >> 6, lane = tid & 63;
  const float scale = 0.125f;
  for (int l = wid; l < CTX; l += 4){
    float s0 = -1e30f, s1 = -1e30f;
    if (lane <= l){
      float a = 0.f;
      #pragma unroll 8
      for (int d = 0; d < 64; ++d) a += qL[l*65+d]*kL[lane*65+d];
      s0 = a * scale;
    }
    int m1 = lane + 64;
    if (l >= 64 && m1 <= l){
      float a = 0.f;
      #pragma unroll 8
      for (int d = 0; d < 64; ++d) a += qL[l*65+d]*kL[m1*65+d];
      s1 = a * scale;
    }
    float mx = wmax(fmaxf(s0, s1));
    float e0 = (lane <= l)            ? __expf(s0 - mx) : 0.0f;
    float e1 = (l >= 64 && m1 <= l)   ? __expf(s1 - mx) : 0.0f;
    float sum = wsum(e0 + e1);
    pL[wid][lane] = e0;
    pL[wid][m1]   = e1;
    float inv = 1.0f / sum;
    float a = 0.f;
    int d = lane;
    for (int m = 0; m <= l; ++m) a += pL[wid][m] * vL[m*65+d];
    Y[((long long)b*CTX + l)*WIDTH + h*64 + d] = f2b(a * inv);
  }
}

// -------- gather EOT+LP-1 rows, final LN -> FI (bf16 [1024,512]) --------
template<bool RF32>
__global__ __launch_bounds__(256) void k_lnf_gather(
    const void* __restrict__ Hp, const int* __restrict__ posy,
    const float* __restrict__ w, const float* __restrict__ b,
    ushort_t* __restrict__ FI)
{
  int wid = threadIdx.x >> 6, lane = threadIdx.x & 63;
  int r = blockIdx.x * 4 + wid;
  if (r >= BSEQ) return;
  int n = r % NTXT;
  int tok = posy[n] + LPROMPT - 1;
  long long row = (long long)r*CTX + tok;
  float v[8];
  if constexpr (RF32){
    const float* x = (const float*)Hp + row * WIDTH;
    #pragma unroll
    for (int i = 0; i < 8; ++i) v[i] = x[lane*8 + i];
  } else {
    const ushort_t* x = (const ushort_t*)Hp + row * WIDTH;
    int4 raw = *(const int4*)(x + lane*8);
    ushort_t* u = (ushort_t*)&raw;
    #pragma unroll
    for (int i = 0; i < 8; ++i) v[i] = b2f(u[i]);
  }
  float s = 0.f, ss = 0.f;
  #pragma unroll
  for (int i = 0; i < 8; ++i){ s += v[i]; ss += v[i]*v[i]; }
  s = wsum(s); ss = wsum(ss);
  float mean = s * (1.0f/WIDTH);
  float var  = ss * (1.0f/WIDTH) - mean*mean;
  float rs = rsqrtf(var + 1e-5f);
  ushort_t o[8];
  #pragma unroll
  for (int i = 0; i < 8; ++i){
    int d = lane*8 + i;
    o[i] = f2b((v[i]-mean)*rs*w[d] + b[d]);
  }
  *(int4*)(FI + (long long)r*WIDTH + lane*8) = *(int4*)o;
}

// -------- final projection: F[1024,1024] = FI[1024,512](bf16) @ TP[512,1024](fp32) --------
__global__ __launch_bounds__(256) void k_fproj(
    const ushort_t* __restrict__ FI, const float* __restrict__ TP,
    float* __restrict__ F)
{
  int idx = blockIdx.x * 256 + threadIdx.x;
  int e = idx & (EMBED-1);
  int m = idx >> 10;
  float acc = 0.f;
  #pragma unroll 8
  for (int k = 0; k < WIDTH; ++k)
    acc += b2f(FI[m*WIDTH + k]) * TP[k*EMBED + e];
  F[idx] = acc;
}

// -------- per-row L2 normalize in place --------
__global__ __launch_bounds__(256) void k_rownorm(float* __restrict__ F)
{
  __shared__ float red[4];
  int r = blockIdx.x;
  float* x = F + (long long)r*EMBED;
  float ss = 0.f;
  for (int i = threadIdx.x; i < EMBED; i += 256){ float v = x[i]; ss += v*v; }
  ss = wsum(ss);
  int wid = threadIdx.x >> 6, lane = threadIdx.x & 63;
  if (lane == 0) red[wid] = ss;
  __syncthreads();
  float inv = rsqrtf(red[0]+red[1]+red[2]+red[3]);
  for (int i = threadIdx.x; i < EMBED; i += 256) x[i] *= inv;
}

// -------- mean over n, normalize, write fp32 out --------
__global__ __launch_bounds__(256) void k_meannorm(
    const float* __restrict__ F, float* __restrict__ OUT)
{
  __shared__ float red[4];
  int p = blockIdx.x;
  float m[4]; float ss = 0.f;
  #pragma unroll
  for (int j = 0; j < 4; ++j){
    int e = threadIdx.x + j*256;
    float s = 0.f;
    for (int n = 0; n < NTXT; ++n) s += F[((long long)(p*NTXT + n))*EMBED + e];
    s *= (1.0f/NTXT);
    m[j] = s; ss += s*s;
  }
  ss = wsum(ss);
  int wid = threadIdx.x >> 6, lane = threadIdx.x & 63;
  if (lane == 0) red[wid] = ss;
  __syncthreads();
  float inv = rsqrtf(red[0]+red[1]+red[2]+red[3]);
  #pragma unroll
  for (int j = 0; j < 4; ++j)
    OUT[p*EMBED + threadIdx.x + j*256] = m[j]*inv;
}

// ============================ launcher ============================

template<bool RF32>
static void run_all(const int* text, const float* cprompt, const float* tok_emb,
                    const float* pos_emb, const float* qkv_w, const float* qkv_b,
                    const float* out_w, const float* out_b, const float* ln1_w,
                    const float* ln1_b, const float* ln2_w, const float* ln2_b,
                    const float* fc_w, const float* fc_b, const float* proj_w,
                    const float* proj_b, const float* lnf_w, const float* lnf_b,
                    const float* tproj, int* posy, void* H, ushort_t* Y, ushort_t* BIG,
                    ushort_t* FI, float* F, float* OUT, int sc, hipStream_t stream)
{
  const int rows_c = ROWS / sc;       // multiple of 128 for sc in {1,2,4,8}
  const int seqs_c = BSEQ / sc;

  k_posy<<<1, 128, 0, stream>>>(text, posy);
  k_embed<RF32><<<(ROWS*512)/256, 256, 0, stream>>>(text, cprompt, tok_emb, pos_emb, posy, H);

  for (int L = 0; L < LAYERS; ++L){
    k_ln<RF32><<<ROWS/4, 256, 0, stream>>>(H, ln1_w + L*WIDTH, ln1_b + L*WIDTH, Y, ROWS);
    for (int c = 0; c < sc; ++c){
      size_t r0 = (size_t)c * rows_c;
      k_gemm<0,RF32><<<dim3(12, rows_c/128), 256, 0, stream>>>(
          Y + r0*WIDTH, qkv_w + (size_t)L*1536*512, qkv_b + L*1536,
          nullptr, BIG, 512, 1536);
      k_attn<<<seqs_c*HEADS, 256, 0, stream>>>(BIG, Y + r0*WIDTH);
    }
    k_gemm<2,RF32><<<dim3(4, ROWS/128), 256, 0, stream>>>(
        Y, out_w + (size_t)L*512*512, out_b + L*512, H, nullptr, 512, 512);
    k_ln<RF32><<<ROWS/4, 256, 0, stream>>>(H, ln2_w + L*WIDTH, ln2_b + L*WIDTH, Y, ROWS);
    for (int c = 0; c < sc; ++c){
      size_t r0 = (size_t)c * rows_c;
      void* Hoff = RF32 ? (void*)((float*)H + r0*WIDTH) : (void*)((ushort_t*)H + r0*WIDTH);
      k_gemm<1,RF32><<<dim3(16, rows_c/128), 256, 0, stream>>>(
          Y + r0*WIDTH, fc_w + (size_t)L*2048*512, fc_b + L*2048,
          nullptr, BIG, 512, 2048);
      k_gemm<2,RF32><<<dim3(4, rows_c/128), 256, 0, stream>>>(
          BIG, proj_w + (size_t)L*512*2048, proj_b + L*512, Hoff, nullptr, 2048, 512);
    }
  }

  k_lnf_gather<RF32><<<BSEQ/4, 256, 0, stream>>>(H, posy, lnf_w, lnf_b, FI);
  k_fproj<<<(BSEQ*EMBED)/256, 256, 0, stream>>>(FI, tproj, F);
  k_rownorm<<<BSEQ, 256, 0, stream>>>(F);
  k_meannorm<<<PP, 256, 0, stream>>>(F, OUT);
}

extern "C" void kernel_launch(void* const* d_in, const int* in_sizes, int n_in,
                              void* d_out, int out_size, void* d_ws, size_t ws_size,
                              hipStream_t stream)
{
  const int*   text    = (const int*)d_in[0];
  const float* cprompt = (const float*)d_in[1];
  const float* tok_emb = (const float*)d_in[2];
  const float* pos_emb = (const float*)d_in[3];
  const float* qkv_w   = (const float*)d_in[4];
  const float* qkv_b   = (const float*)d_in[5];
  const float* out_w   = (const float*)d_in[6];
  const float* out_b   = (const float*)d_in[7];
  const float* ln1_w   = (const float*)d_in[8];
  const float* ln1_b   = (const float*)d_in[9];
  const float* ln2_w   = (const float*)d_in[10];
  const float* ln2_b   = (const float*)d_in[11];
  const float* fc_w    = (const float*)d_in[12];
  const float* fc_b    = (const float*)d_in[13];
  const float* proj_w  = (const float*)d_in[14];
  const float* proj_b  = (const float*)d_in[15];
  const float* lnf_w   = (const float*)d_in[16];
  const float* lnf_b   = (const float*)d_in[17];
  const float* tproj   = (const float*)d_in[18];

  // ---- choose config that fits ws_size ----
  auto al = [](size_t b){ return (b + 255) & ~(size_t)255; };
  const size_t fixed = al(NTXT*sizeof(int)) + al((size_t)ROWS*WIDTH*2 /*Y*/)
                     + al((size_t)BSEQ*WIDTH*2 /*FI*/) + al((size_t)BSEQ*EMBED*4 /*F*/);
  int sc = 8; bool hf32 = false;           // last-resort fallback
  const int scs[4] = {1, 2, 4, 8};
  bool found = false;
  for (int pass = 0; pass < 2 && !found; ++pass){   // pass 0: fp32 H, pass 1: bf16 H
    size_t hbytes = (size_t)ROWS*WIDTH*(pass == 0 ? 4 : 2);
    for (int i = 0; i < 4; ++i){
      size_t big = (size_t)(ROWS/scs[i]) * 2048 * 2;
      if (fixed + al(hbytes) + al(big) <= ws_size){
        sc = scs[i]; hf32 = (pass == 0); found = true; break;
      }
    }
  }

  char* ws = (char*)d_ws;
  size_t off = 0;
  auto alloc = [&](size_t bytes)->char*{
    char* pp = ws + off; off += (bytes + 255) & ~(size_t)255; return pp;
  };
  int*      posy = (int*)     alloc(NTXT*sizeof(int));
  void*     H    = (void*)    alloc((size_t)ROWS*WIDTH*(hf32 ? 4 : 2));
  ushort_t* Y    = (ushort_t*)alloc((size_t)ROWS*WIDTH*2);
  ushort_t* BIG  = (ushort_t*)alloc((size_t)(ROWS/sc)*2048*2);
  ushort_t* FI   = (ushort_t*)alloc((size_t)BSEQ*WIDTH*2);
  float*    F    = (float*)   alloc((size_t)BSEQ*EMBED*4);

  if (hf32)
    run_all<true >(text, cprompt, tok_emb, pos_emb, qkv_w, qkv_b, out_w, out_b,
                   ln1_w, ln1_b, ln2_w, ln2_b, fc_w, fc_b, proj_w, proj_b,
                   lnf_w, lnf_b, tproj, posy, H, Y, BIG, FI, F,
                   (float*)d_out, sc, stream);
  else
    run_all<false>(text, cprompt, tok_emb, pos_emb, qkv_w, qkv_b, out_w, out_b,
                   ln1_w, ln1_b, ln2_w, ln2_b, fc_w, fc_b, proj_w, proj_b,
                   lnf_w, lnf_b, tproj, posy, H, Y, BIG, FI, F,
                   (float*)d_out, sc, stream);
}

// Round 4
// 18944.800 us; speedup vs baseline: 1.3468x; 1.3468x over previous
//
#include <hip/hip_runtime.h>
#include <math.h>

#define CTX 77
#define WIDTH 512
#define HEADS 8
#define DH 64
#define LAYERS 12
#define EMBED 1024
#define NTXT 128
#define PP 8
#define LPROMPT 16
#define EOTTOK 49407
#define BSEQ (PP*NTXT)          // 1024
#define ROWS (BSEQ*CTX)         // 78848

typedef unsigned short ushort_t;
typedef __attribute__((ext_vector_type(8))) short short8;
typedef __attribute__((ext_vector_type(4))) float floatx4;

__device__ __forceinline__ float b2f(ushort_t u){
  union { unsigned int i; float f; } x; x.i = ((unsigned int)u) << 16; return x.f;
}
__device__ __forceinline__ ushort_t f2b(float f){
  union { float f; unsigned int i; } x; x.f = f;
  unsigned int r = x.i + 0x7fffu + ((x.i >> 16) & 1u);
  return (ushort_t)(r >> 16);
}
__device__ __forceinline__ float wsum(float v){
  #pragma unroll
  for (int o = 32; o > 0; o >>= 1) v += __shfl_xor(v, o, 64);
  return v;
}
__device__ __forceinline__ float wmax(float v){
  #pragma unroll
  for (int o = 32; o > 0; o >>= 1) v = fmaxf(v, __shfl_xor(v, o, 64));
  return v;
}

// -------- fp32 -> bf16 weight conversion (RNE), 4 elems/thread --------
__global__ __launch_bounds__(256) void k_conv(
    const float* __restrict__ s, ushort_t* __restrict__ d, int n4)
{
  int i = blockIdx.x * 256 + threadIdx.x;
  if (i < n4){
    float4 v = ((const float4*)s)[i];
    ushort_t o[4] = { f2b(v.x), f2b(v.y), f2b(v.z), f2b(v.w) };
    ((int2*)d)[i] = *(int2*)o;
  }
}

// -------- pos_y: first EOT position per text row --------
__global__ void k_posy(const int* __restrict__ text, int* __restrict__ posy){
  int n = threadIdx.x;
  if (n < NTXT){
    int p = 0;
    for (int t = 0; t < CTX; ++t){ if (text[n*CTX + t] == EOTTOK){ p = t; break; } }
    posy[n] = p;
  }
}

// -------- embedding + prompt splice + pos_emb -> H --------
template<bool RF32>
__global__ __launch_bounds__(256) void k_embed(
    const int* __restrict__ text, const float* __restrict__ cprompt,
    const float* __restrict__ tok_emb, const float* __restrict__ pos_emb,
    const int* __restrict__ posy, void* __restrict__ Hp)
{
  long long idx = (long long)blockIdx.x * 256 + threadIdx.x;
  int d   = (int)(idx & 511);
  int row = (int)(idx >> 9);
  int t  = row % CTX;
  int pn = row / CTX;
  int n  = pn % NTXT;
  int p  = pn / NTXT;
  int py = posy[n];
  float v;
  if (t >= py && t < py + LPROMPT){
    int pidx = t - py;
    v = cprompt[(p*LPROMPT + pidx)*WIDTH + d];
  } else {
    int src = (t < py) ? t : (t - LPROMPT + 1);
    src = min(max(src, 0), CTX-1);
    int tok = text[n*CTX + src];
    v = tok_emb[(long long)tok*WIDTH + d];
  }
  v += pos_emb[t*WIDTH + d];
  if constexpr (RF32) ((float*)Hp)[idx] = v;
  else                ((ushort_t*)Hp)[idx] = f2b(v);
}

// -------- LayerNorm: H -> Y(bf16), one wave per 512-row --------
template<bool RF32>
__global__ __launch_bounds__(256) void k_ln(
    const void* __restrict__ Hp, const float* __restrict__ w,
    const float* __restrict__ b, ushort_t* __restrict__ Y, int nrows)
{
  int wid = threadIdx.x >> 6, lane = threadIdx.x & 63;
  int row = blockIdx.x * 4 + wid;
  if (row >= nrows) return;
  float v[8];
  if constexpr (RF32){
    const float* x = (const float*)Hp + (long long)row * WIDTH;
    #pragma unroll
    for (int i = 0; i < 8; ++i) v[i] = x[lane*8 + i];
  } else {
    const ushort_t* x = (const ushort_t*)Hp + (long long)row * WIDTH;
    int4 raw = *(const int4*)(x + lane*8);
    ushort_t* u = (ushort_t*)&raw;
    #pragma unroll
    for (int i = 0; i < 8; ++i) v[i] = b2f(u[i]);
  }
  float s = 0.f, ss = 0.f;
  #pragma unroll
  for (int i = 0; i < 8; ++i){ s += v[i]; ss += v[i]*v[i]; }
  s = wsum(s); ss = wsum(ss);
  float mean = s * (1.0f/WIDTH);
  float var  = ss * (1.0f/WIDTH) - mean*mean;
  float rs = rsqrtf(var + 1e-5f);
  ushort_t o[8];
  #pragma unroll
  for (int i = 0; i < 8; ++i){
    int d = lane*8 + i;
    o[i] = f2b((v[i]-mean)*rs*w[d] + b[d]);
  }
  *(int4*)(Y + (long long)row*WIDTH + lane*8) = *(int4*)o;
}

// -------- GEMM: C[M,N] = A[M,K](bf16) @ W[N,K]^T(bf16) + bias(fp32) --------
// MODE 0: O=bf16(acc+bias)  MODE 1: O=bf16(gelu(acc+bias))  MODE 2: H += acc+bias
template<int MODE, bool RF32>
__global__ __launch_bounds__(256) void k_gemm(
    const ushort_t* __restrict__ A, const ushort_t* __restrict__ W,
    const float* __restrict__ bias, void* __restrict__ Hp,
    ushort_t* __restrict__ O, int K, int N)
{
  __shared__ ushort_t As[128*32];
  __shared__ ushort_t Bs[128*32];
  int tid  = threadIdx.x;
  int lane = tid & 63, wid = tid >> 6;
  int wm = wid >> 1, wn = wid & 1;
  long long m0 = (long long)blockIdx.y * 128;
  int n0 = blockIdx.x * 128;

  floatx4 acc[4][4];
  #pragma unroll
  for (int i = 0; i < 4; ++i)
    #pragma unroll
    for (int j = 0; j < 4; ++j){ floatx4 z = {0.f,0.f,0.f,0.f}; acc[i][j] = z; }

  int e0 = tid*8, e1 = (256+tid)*8;
  int r0 = e0 >> 5, c0 = e0 & 31;
  int r1 = e1 >> 5, c1 = e1 & 31;

  for (int k0 = 0; k0 < K; k0 += 32){
    int4 a0 = *(const int4*)(A + (m0 + r0)*K + k0 + c0);
    int4 a1 = *(const int4*)(A + (m0 + r1)*K + k0 + c1);
    int4 b0 = *(const int4*)(W + (size_t)(n0 + r0)*K + k0 + c0);
    int4 b1 = *(const int4*)(W + (size_t)(n0 + r1)*K + k0 + c1);
    __syncthreads();
    *(int4*)(As + e0) = a0; *(int4*)(As + e1) = a1;
    *(int4*)(Bs + e0) = b0; *(int4*)(Bs + e1) = b1;
    __syncthreads();
    int quad = lane >> 4, r = lane & 15;
    short8 af[4], bf[4];
    #pragma unroll
    for (int i = 0; i < 4; ++i) af[i] = *(const short8*)(As + (wm*64 + i*16 + r)*32 + quad*8);
    #pragma unroll
    for (int j = 0; j < 4; ++j) bf[j] = *(const short8*)(Bs + (wn*64 + j*16 + r)*32 + quad*8);
    #pragma unroll
    for (int i = 0; i < 4; ++i)
      #pragma unroll
      for (int j = 0; j < 4; ++j)
        acc[i][j] = __builtin_amdgcn_mfma_f32_16x16x32_bf16(af[i], bf[j], acc[i][j], 0, 0, 0);
  }

  int quad = lane >> 4, cn = lane & 15;
  #pragma unroll
  for (int i = 0; i < 4; ++i){
    #pragma unroll
    for (int j = 0; j < 4; ++j){
      int gcol = n0 + wn*64 + j*16 + cn;
      float bv = bias[gcol];
      #pragma unroll
      for (int rg = 0; rg < 4; ++rg){
        long long grow = m0 + wm*64 + i*16 + quad*4 + rg;
        float v = acc[i][j][rg] + bv;
        if (MODE == 0){
          O[grow*N + gcol] = f2b(v);
        } else if (MODE == 1){
          float g = v / (1.0f + __expf(-1.702f*v));
          O[grow*N + gcol] = f2b(g);
        } else {
          long long idx = grow*N + gcol;
          if constexpr (RF32) ((float*)Hp)[idx] += v;
          else { ushort_t* hb = (ushort_t*)Hp; hb[idx] = f2b(b2f(hb[idx]) + v); }
        }
      }
    }
  }
}

// -------- MFMA causal attention: one block per (seq b, head h) --------
// QKV[b,77,1536](bf16) -> Y[b,77,512](bf16)
// LDS plan (55,872 B):
//   [0,11520)        Qs  bf16 [80][72]   (dead after S phase)
//   [11520,23040)    Ks  bf16 [80][72]   (dead after S phase)
//   [0,25920)        Ss  f32  [80][81]   (overlays Qs/Ks after S phase)
//   [25920,39232)    Vt  bf16 [64][104]  (V transposed, keys padded to 96)
//   [39232,55872)    Ps  bf16 [80][104]  (normalized probs, zero-padded)
__global__ __launch_bounds__(256) void k_attn(
    const ushort_t* __restrict__ QKV, ushort_t* __restrict__ Y)
{
  __shared__ char smem[55872];
  ushort_t* Qs = (ushort_t*)smem;
  ushort_t* Ks = (ushort_t*)(smem + 11520);
  float*    Ss = (float*)smem;
  ushort_t* Vt = (ushort_t*)(smem + 25920);
  ushort_t* Ps = (ushort_t*)(smem + 39232);

  int b = blockIdx.x >> 3, h = blockIdx.x & 7;
  int tid = threadIdx.x;
  int lane = tid & 63, wid = tid >> 6;
  int quad = lane >> 4, r = lane & 15;
  const ushort_t* base = QKV + (size_t)b*CTX*1536 + h*64;

  // ---- stage 1: load Q,K (row-major, stride 72) and V transposed (stride 104) ----
  #pragma unroll
  for (int it = 0; it < 5; ++it){
    int id = tid + it*256;            // 0..1279 = 80 rows * 16 chunks
    int t  = id >> 4;
    int d4 = (id & 15) * 4;
    ushort_t q[4], k[4], v[4];
    if (t < CTX){
      const ushort_t* rp = base + (size_t)t*1536 + d4;
      *(int2*)q = *(const int2*)(rp);
      *(int2*)k = *(const int2*)(rp + 512);
      *(int2*)v = *(const int2*)(rp + 1024);
    } else {
      q[0]=q[1]=q[2]=q[3]=0; k[0]=k[1]=k[2]=k[3]=0; v[0]=v[1]=v[2]=v[3]=0;
    }
    *(int2*)(Qs + t*72 + d4) = *(int2*)q;
    *(int2*)(Ks + t*72 + d4) = *(int2*)k;
    #pragma unroll
    for (int i = 0; i < 4; ++i) Vt[(d4+i)*104 + t] = v[i];
  }
  { // zero Vt key-columns 80..95
    int z = tid * 4;                  // 1024 elems = 64 d * 16 cols
    int d = z >> 4, c = 80 + (z & 15);
    ushort_t zz[4] = {0,0,0,0};
    *(int2*)(Vt + d*104 + c) = *(int2*)zz;
  }
  __syncthreads();

  // ---- stage 2: S = scale * Q K^T, lower-tri 16x16 tiles, held in registers ----
  const int TI[15] = {0,1,1,2,2,2,3,3,3,3,4,4,4,4,4};
  const int TJ[15] = {0,0,1,0,1,2,0,1,2,3,0,1,2,3,4};
  floatx4 cS[4];
  int ntile = 0;
  for (int tt = wid; tt < 15; tt += 4, ++ntile){
    int i = TI[tt], j = TJ[tt];
    floatx4 c = {0.f,0.f,0.f,0.f};
    #pragma unroll
    for (int s = 0; s < 2; ++s){
      short8 aq = *(const short8*)(Qs + (i*16 + r)*72 + s*32 + quad*8);
      short8 bk = *(const short8*)(Ks + (j*16 + r)*72 + s*32 + quad*8);
      c = __builtin_amdgcn_mfma_f32_16x16x32_bf16(aq, bk, c, 0, 0, 0);
    }
    cS[ntile] = c;
  }
  __syncthreads();   // Qs/Ks dead; Ss region may now be written

  {
    int idx = 0;
    for (int tt = wid; tt < 15; tt += 4, ++idx){
      int i = TI[tt], j = TJ[tt];
      #pragma unroll
      for (int rg = 0; rg < 4; ++rg){
        int q  = i*16 + quad*4 + rg;
        int kk = j*16 + r;
        float s = cS[idx][rg] * 0.125f;
        if (kk > q) s = -1e30f;
        Ss[q*81 + kk] = s;
      }
    }
  }
  __syncthreads();

  // ---- stage 3: row softmax -> Ps (normalized, bf16, cols 0..95) ----
  for (int q = wid; q < 80; q += 4){
    if (q >= CTX){
      Ps[q*104 + lane] = 0;
      if (lane < 32) Ps[q*104 + 64 + lane] = 0;
      continue;
    }
    int k1 = 64 + lane;
    float s0 = (lane <= q) ? Ss[q*81 + lane] : -1e30f;
    float s1 = (k1  <= q) ? Ss[q*81 + k1 ]  : -1e30f;
    float mx = wmax(fmaxf(s0, s1));
    float e0 = (lane <= q) ? __expf(s0 - mx) : 0.0f;
    float e1 = (k1  <= q) ? __expf(s1 - mx) : 0.0f;
    float inv = 1.0f / wsum(e0 + e1);
    Ps[q*104 + lane] = f2b(e0 * inv);
    if (lane < 32) Ps[q*104 + 64 + lane] = f2b(e1 * inv);
  }
  __syncthreads();

  // ---- stage 4: O = P V via 5x4 tiles, K=96 ----
  for (int tt = wid; tt < 20; tt += 4){
    int mi = tt >> 2, ni = tt & 3;
    floatx4 c = {0.f,0.f,0.f,0.f};
    #pragma unroll
    for (int kc = 0; kc < 3; ++kc){
      short8 ap = *(const short8*)(Ps + (mi*16 + r)*104 + kc*32 + quad*8);
      short8 bv = *(const short8*)(Vt + (ni*16 + r)*104 + kc*32 + quad*8);
      c = __builtin_amdgcn_mfma_f32_16x16x32_bf16(ap, bv, c, 0, 0, 0);
    }
    #pragma unroll
    for (int rg = 0; rg < 4; ++rg){
      int q = mi*16 + quad*4 + rg;
      if (q < CTX)
        Y[((size_t)b*CTX + q)*WIDTH + h*64 + ni*16 + r] = f2b(c[rg]);
    }
  }
}

// -------- gather EOT+LP-1 rows, final LN -> FI (bf16 [1024,512]) --------
template<bool RF32>
__global__ __launch_bounds__(256) void k_lnf_gather(
    const void* __restrict__ Hp, const int* __restrict__ posy,
    const float* __restrict__ w, const float* __restrict__ b,
    ushort_t* __restrict__ FI)
{
  int wid = threadIdx.x >> 6, lane = threadIdx.x & 63;
  int rr = blockIdx.x * 4 + wid;
  if (rr >= BSEQ) return;
  int n = rr % NTXT;
  int tok = posy[n] + LPROMPT - 1;
  long long row = (long long)rr*CTX + tok;
  float v[8];
  if constexpr (RF32){
    const float* x = (const float*)Hp + row * WIDTH;
    #pragma unroll
    for (int i = 0; i < 8; ++i) v[i] = x[lane*8 + i];
  } else {
    const ushort_t* x = (const ushort_t*)Hp + row * WIDTH;
    int4 raw = *(const int4*)(x + lane*8);
    ushort_t* u = (ushort_t*)&raw;
    #pragma unroll
    for (int i = 0; i < 8; ++i) v[i] = b2f(u[i]);
  }
  float s = 0.f, ss = 0.f;
  #pragma unroll
  for (int i = 0; i < 8; ++i){ s += v[i]; ss += v[i]*v[i]; }
  s = wsum(s); ss = wsum(ss);
  float mean = s * (1.0f/WIDTH);
  float var  = ss * (1.0f/WIDTH) - mean*mean;
  float rs = rsqrtf(var + 1e-5f);
  ushort_t o[8];
  #pragma unroll
  for (int i = 0; i < 8; ++i){
    int d = lane*8 + i;
    o[i] = f2b((v[i]-mean)*rs*w[d] + b[d]);
  }
  *(int4*)(FI + (long long)rr*WIDTH + lane*8) = *(int4*)o;
}

// -------- final projection: F[1024,1024] = FI[1024,512](bf16) @ TP[512,1024](fp32) --------
__global__ __launch_bounds__(256) void k_fproj(
    const ushort_t* __restrict__ FI, const float* __restrict__ TP,
    float* __restrict__ F)
{
  int idx = blockIdx.x * 256 + threadIdx.x;
  int e = idx & (EMBED-1);
  int m = idx >> 10;
  float acc = 0.f;
  #pragma unroll 8
  for (int k = 0; k < WIDTH; ++k)
    acc += b2f(FI[m*WIDTH + k]) * TP[k*EMBED + e];
  F[idx] = acc;
}

// -------- per-row L2 normalize in place --------
__global__ __launch_bounds__(256) void k_rownorm(float* __restrict__ F)
{
  __shared__ float red[4];
  int rr = blockIdx.x;
  float* x = F + (long long)rr*EMBED;
  float ss = 0.f;
  for (int i = threadIdx.x; i < EMBED; i += 256){ float v = x[i]; ss += v*v; }
  ss = wsum(ss);
  int wid = threadIdx.x >> 6, lane = threadIdx.x & 63;
  if (lane == 0) red[wid] = ss;
  __syncthreads();
  float inv = rsqrtf(red[0]+red[1]+red[2]+red[3]);
  for (int i = threadIdx.x; i < EMBED; i += 256) x[i] *= inv;
}

// -------- mean over n, normalize, write fp32 out --------
__global__ __launch_bounds__(256) void k_meannorm(
    const float* __restrict__ F, float* __restrict__ OUT)
{
  __shared__ float red[4];
  int p = blockIdx.x;
  float m[4]; float ss = 0.f;
  #pragma unroll
  for (int j = 0; j < 4; ++j){
    int e = threadIdx.x + j*256;
    float s = 0.f;
    for (int n = 0; n < NTXT; ++n) s += F[((long long)(p*NTXT + n))*EMBED + e];
    s *= (1.0f/NTXT);
    m[j] = s; ss += s*s;
  }
  ss = wsum(ss);
  int wid = threadIdx.x >> 6, lane = threadIdx.x & 63;
  if (lane == 0) red[wid] = ss;
  __syncthreads();
  float inv = rsqrtf(red[0]+red[1]+red[2]+red[3]);
  #pragma unroll
  for (int j = 0; j < 4; ++j)
    OUT[p*EMBED + threadIdx.x + j*256] = m[j]*inv;
}

// ============================ launcher ============================

template<bool RF32>
static void run_all(const int* text, const float* cprompt, const float* tok_emb,
                    const float* pos_emb,
                    const ushort_t* Wqkv, const float* qkv_b,
                    const ushort_t* Wout, const float* out_b,
                    const float* ln1_w, const float* ln1_b,
                    const float* ln2_w, const float* ln2_b,
                    const ushort_t* Wfc, const float* fc_b,
                    const ushort_t* Wproj, const float* proj_b,
                    const float* lnf_w, const float* lnf_b, const float* tproj,
                    int* posy, void* H, ushort_t* Y, ushort_t* BIG,
                    ushort_t* FI, float* F, float* OUT, int sc, hipStream_t stream)
{
  const int rows_c = ROWS / sc;       // multiple of 128 for sc in {1,2,4,8}
  const int seqs_c = BSEQ / sc;

  k_posy<<<1, 128, 0, stream>>>(text, posy);
  k_embed<RF32><<<(ROWS*512)/256, 256, 0, stream>>>(text, cprompt, tok_emb, pos_emb, posy, H);

  for (int L = 0; L < LAYERS; ++L){
    k_ln<RF32><<<ROWS/4, 256, 0, stream>>>(H, ln1_w + L*WIDTH, ln1_b + L*WIDTH, Y, ROWS);
    for (int c = 0; c < sc; ++c){
      size_t r0 = (size_t)c * rows_c;
      k_gemm<0,RF32><<<dim3(12, rows_c/128), 256, 0, stream>>>(
          Y + r0*WIDTH, Wqkv + (size_t)L*1536*512, qkv_b + L*1536,
          nullptr, BIG, 512, 1536);
      k_attn<<<seqs_c*HEADS, 256, 0, stream>>>(BIG, Y + r0*WIDTH);
    }
    k_gemm<2,RF32><<<dim3(4, ROWS/128), 256, 0, stream>>>(
        Y, Wout + (size_t)L*512*512, out_b + L*512, H, nullptr, 512, 512);
    k_ln<RF32><<<ROWS/4, 256, 0, stream>>>(H, ln2_w + L*WIDTH, ln2_b + L*WIDTH, Y, ROWS);
    for (int c = 0; c < sc; ++c){
      size_t r0 = (size_t)c * rows_c;
      void* Hoff = RF32 ? (void*)((float*)H + r0*WIDTH) : (void*)((ushort_t*)H + r0*WIDTH);
      k_gemm<1,RF32><<<dim3(16, rows_c/128), 256, 0, stream>>>(
          Y + r0*WIDTH, Wfc + (size_t)L*2048*512, fc_b + L*2048,
          nullptr, BIG, 512, 2048);
      k_gemm<2,RF32><<<dim3(4, rows_c/128), 256, 0, stream>>>(
          BIG, Wproj + (size_t)L*512*2048, proj_b + L*512, Hoff, nullptr, 2048, 512);
    }
  }

  k_lnf_gather<RF32><<<BSEQ/4, 256, 0, stream>>>(H, posy, lnf_w, lnf_b, FI);
  k_fproj<<<(BSEQ*EMBED)/256, 256, 0, stream>>>(FI, tproj, F);
  k_rownorm<<<BSEQ, 256, 0, stream>>>(F);
  k_meannorm<<<PP, 256, 0, stream>>>(F, OUT);
}

extern "C" void kernel_launch(void* const* d_in, const int* in_sizes, int n_in,
                              void* d_out, int out_size, void* d_ws, size_t ws_size,
                              hipStream_t stream)
{
  const int*   text    = (const int*)d_in[0];
  const float* cprompt = (const float*)d_in[1];
  const float* tok_emb = (const float*)d_in[2];
  const float* pos_emb = (const float*)d_in[3];
  const float* qkv_w   = (const float*)d_in[4];
  const float* qkv_b   = (const float*)d_in[5];
  const float* out_w   = (const float*)d_in[6];
  const float* out_b   = (const float*)d_in[7];
  const float* ln1_w   = (const float*)d_in[8];
  const float* ln1_b   = (const float*)d_in[9];
  const float* ln2_w   = (const float*)d_in[10];
  const float* ln2_b   = (const float*)d_in[11];
  const float* fc_w    = (const float*)d_in[12];
  const float* fc_b    = (const float*)d_in[13];
  const float* proj_w  = (const float*)d_in[14];
  const float* proj_b  = (const float*)d_in[15];
  const float* lnf_w   = (const float*)d_in[16];
  const float* lnf_b   = (const float*)d_in[17];
  const float* tproj   = (const float*)d_in[18];

  // bf16 weight copy sizes (elements)
  const size_t nQKV = (size_t)LAYERS*1536*512;   // 9,437,184
  const size_t nOUT = (size_t)LAYERS*512*512;    // 3,145,728
  const size_t nFC  = (size_t)LAYERS*2048*512;   // 12,582,912
  const size_t nPRJ = (size_t)LAYERS*512*2048;   // 12,582,912
  const size_t nWB  = nQKV + nOUT + nFC + nPRJ;  // 37,748,736 elems -> 72 MB bf16

  // ---- choose config that fits ws_size ----
  auto al = [](size_t b){ return (b + 255) & ~(size_t)255; };
  const size_t fixed = al(NTXT*sizeof(int)) + al((size_t)ROWS*WIDTH*2 /*Y*/)
                     + al((size_t)BSEQ*WIDTH*2 /*FI*/) + al((size_t)BSEQ*EMBED*4 /*F*/)
                     + al(nWB*2);
  int sc = 8; bool hf32 = false;           // last-resort fallback
  const int scs[4] = {1, 2, 4, 8};
  bool found = false;
  for (int pass = 0; pass < 2 && !found; ++pass){   // pass 0: fp32 H, pass 1: bf16 H
    size_t hbytes = (size_t)ROWS*WIDTH*(pass == 0 ? 4 : 2);
    for (int i = 0; i < 4; ++i){
      size_t big = (size_t)(ROWS/scs[i]) * 2048 * 2;
      if (fixed + al(hbytes) + al(big) <= ws_size){
        sc = scs[i]; hf32 = (pass == 0); found = true; break;
      }
    }
  }

  char* ws = (char*)d_ws;
  size_t off = 0;
  auto alloc = [&](size_t bytes)->char*{
    char* pp = ws + off; off += (bytes + 255) & ~(size_t)255; return pp;
  };
  int*      posy = (int*)     alloc(NTXT*sizeof(int));
  void*     H    = (void*)    alloc((size_t)ROWS*WIDTH*(hf32 ? 4 : 2));
  ushort_t* Y    = (ushort_t*)alloc((size_t)ROWS*WIDTH*2);
  ushort_t* BIG  = (ushort_t*)alloc((size_t)(ROWS/sc)*2048*2);
  ushort_t* FI   = (ushort_t*)alloc((size_t)BSEQ*WIDTH*2);
  float*    F    = (float*)   alloc((size_t)BSEQ*EMBED*4);
  ushort_t* WB   = (ushort_t*)alloc(nWB*2);
  ushort_t* Wqkv = WB;
  ushort_t* Wout = WB + nQKV;
  ushort_t* Wfc  = WB + nQKV + nOUT;
  ushort_t* Wprj = WB + nQKV + nOUT + nFC;

  // convert weights fp32 -> bf16 once per call
  k_conv<<<(int)((nQKV/4 + 255)/256), 256, 0, stream>>>(qkv_w,  Wqkv, (int)(nQKV/4));
  k_conv<<<(int)((nOUT/4 + 255)/256), 256, 0, stream>>>(out_w,  Wout, (int)(nOUT/4));
  k_conv<<<(int)((nFC /4 + 255)/256), 256, 0, stream>>>(fc_w,   Wfc,  (int)(nFC /4));
  k_conv<<<(int)((nPRJ/4 + 255)/256), 256, 0, stream>>>(proj_w, Wprj, (int)(nPRJ/4));

  if (hf32)
    run_all<true >(text, cprompt, tok_emb, pos_emb, Wqkv, qkv_b, Wout, out_b,
                   ln1_w, ln1_b, ln2_w, ln2_b, Wfc, fc_b, Wprj, proj_b,
                   lnf_w, lnf_b, tproj, posy, H, Y, BIG, FI, F,
                   (float*)d_out, sc, stream);
  else
    run_all<false>(text, cprompt, tok_emb, pos_emb, Wqkv, qkv_b, Wout, out_b,
                   ln1_w, ln1_b, ln2_w, ln2_b, Wfc, fc_b, Wprj, proj_b,
                   lnf_w, lnf_b, tproj, posy, H, Y, BIG, FI, F,
                   (float*)d_out, sc, stream);
}

// Round 5
// 18820.044 us; speedup vs baseline: 1.3558x; 1.0066x over previous
//
#include <hip/hip_runtime.h>
#include <math.h>
#include <stdint.h>

#define CTX 77
#define WIDTH 512
#define HEADS 8
#define DH 64
#define LAYERS 12
#define EMBED 1024
#define NTXT 128
#define PP 8
#define LPROMPT 16
#define EOTTOK 49407
#define BSEQ (PP*NTXT)          // 1024
#define ROWS (BSEQ*CTX)         // 78848

typedef unsigned short ushort_t;
typedef __attribute__((ext_vector_type(8))) short short8;
typedef __attribute__((ext_vector_type(4))) float floatx4;

__device__ __forceinline__ float b2f(ushort_t u){
  union { unsigned int i; float f; } x; x.i = ((unsigned int)u) << 16; return x.f;
}
__device__ __forceinline__ ushort_t f2b(float f){
  union { float f; unsigned int i; } x; x.f = f;
  unsigned int r = x.i + 0x7fffu + ((x.i >> 16) & 1u);
  return (ushort_t)(r >> 16);
}
__device__ __forceinline__ float wsum(float v){
  #pragma unroll
  for (int o = 32; o > 0; o >>= 1) v += __shfl_xor(v, o, 64);
  return v;
}
__device__ __forceinline__ float wmax(float v){
  #pragma unroll
  for (int o = 32; o > 0; o >>= 1) v = fmaxf(v, __shfl_xor(v, o, 64));
  return v;
}

// async global->LDS, 16 B per lane; LDS dest = wave-uniform base + lane*16.
// Casts go through uintptr_t (generic LDS pointer low 32 bits == LDS offset).
__device__ __forceinline__ void async16(const void* g, void* l){
  __builtin_amdgcn_global_load_lds(
      (const __attribute__((address_space(1))) void*)(uintptr_t)g,
      (__attribute__((address_space(3))) void*)(uint32_t)(uintptr_t)l,
      16, 0, 0);
}

// -------- fp32 -> bf16 weight conversion (RNE), 4 elems/thread --------
__global__ __launch_bounds__(256) void k_conv(
    const float* __restrict__ s, ushort_t* __restrict__ d, int n4)
{
  int i = blockIdx.x * 256 + threadIdx.x;
  if (i < n4){
    float4 v = ((const float4*)s)[i];
    ushort_t o[4] = { f2b(v.x), f2b(v.y), f2b(v.z), f2b(v.w) };
    ((int2*)d)[i] = *(int2*)o;
  }
}

// -------- pos_y: first EOT position per text row --------
__global__ void k_posy(const int* __restrict__ text, int* __restrict__ posy){
  int n = threadIdx.x;
  if (n < NTXT){
    int p = 0;
    for (int t = 0; t < CTX; ++t){ if (text[n*CTX + t] == EOTTOK){ p = t; break; } }
    posy[n] = p;
  }
}

// -------- embedding + prompt splice + pos_emb -> H --------
template<bool RF32>
__global__ __launch_bounds__(256) void k_embed(
    const int* __restrict__ text, const float* __restrict__ cprompt,
    const float* __restrict__ tok_emb, const float* __restrict__ pos_emb,
    const int* __restrict__ posy, void* __restrict__ Hp)
{
  long long idx = (long long)blockIdx.x * 256 + threadIdx.x;
  int d   = (int)(idx & 511);
  int row = (int)(idx >> 9);
  int t  = row % CTX;
  int pn = row / CTX;
  int n  = pn % NTXT;
  int p  = pn / NTXT;
  int py = posy[n];
  float v;
  if (t >= py && t < py + LPROMPT){
    int pidx = t - py;
    v = cprompt[(p*LPROMPT + pidx)*WIDTH + d];
  } else {
    int src = (t < py) ? t : (t - LPROMPT + 1);
    src = min(max(src, 0), CTX-1);
    int tok = text[n*CTX + src];
    v = tok_emb[(long long)tok*WIDTH + d];
  }
  v += pos_emb[t*WIDTH + d];
  if constexpr (RF32) ((float*)Hp)[idx] = v;
  else                ((ushort_t*)Hp)[idx] = f2b(v);
}

// -------- LayerNorm: H -> Y(bf16), one wave per 512-row --------
template<bool RF32>
__global__ __launch_bounds__(256) void k_ln(
    const void* __restrict__ Hp, const float* __restrict__ w,
    const float* __restrict__ b, ushort_t* __restrict__ Y, int nrows)
{
  int wid = threadIdx.x >> 6, lane = threadIdx.x & 63;
  int row = blockIdx.x * 4 + wid;
  if (row >= nrows) return;
  float v[8];
  if constexpr (RF32){
    const float* x = (const float*)Hp + (long long)row * WIDTH;
    #pragma unroll
    for (int i = 0; i < 8; ++i) v[i] = x[lane*8 + i];
  } else {
    const ushort_t* x = (const ushort_t*)Hp + (long long)row * WIDTH;
    int4 raw = *(const int4*)(x + lane*8);
    ushort_t* u = (ushort_t*)&raw;
    #pragma unroll
    for (int i = 0; i < 8; ++i) v[i] = b2f(u[i]);
  }
  float s = 0.f, ss = 0.f;
  #pragma unroll
  for (int i = 0; i < 8; ++i){ s += v[i]; ss += v[i]*v[i]; }
  s = wsum(s); ss = wsum(ss);
  float mean = s * (1.0f/WIDTH);
  float var  = ss * (1.0f/WIDTH) - mean*mean;
  float rs = rsqrtf(var + 1e-5f);
  ushort_t o[8];
  #pragma unroll
  for (int i = 0; i < 8; ++i){
    int d = lane*8 + i;
    o[i] = f2b((v[i]-mean)*rs*w[d] + b[d]);
  }
  *(int4*)(Y + (long long)row*WIDTH + lane*8) = *(int4*)o;
}

// -------- GEMM: C[M,N] = A[M,K](bf16) @ W[N,K]^T(bf16) + bias(fp32) --------
// m97-style K-loop: global_load_lds(16B) staging, 128x128 tile, BK=32.
// MODE 0: O=bf16(acc+bias)  MODE 1: O=bf16(gelu(acc+bias))  MODE 2: H += acc+bias
template<int MODE, bool RF32>
__global__ __launch_bounds__(256) void k_gemm(
    const ushort_t* __restrict__ A, const ushort_t* __restrict__ W,
    const float* __restrict__ bias, void* __restrict__ Hp,
    ushort_t* __restrict__ O, int K, int N)
{
  __shared__ ushort_t As[128*32];
  __shared__ ushort_t Bs[128*32];
  int tid  = threadIdx.x;
  int lane = tid & 63, wid = tid >> 6;
  int wm = wid >> 1, wn = wid & 1;
  long long m0 = (long long)blockIdx.y * 128;
  int n0 = blockIdx.x * 128;

  floatx4 acc[4][4];
  #pragma unroll
  for (int i = 0; i < 4; ++i)
    #pragma unroll
    for (int j = 0; j < 4; ++j){ floatx4 z = {0.f,0.f,0.f,0.f}; acc[i][j] = z; }

  // staging geometry: wave wid covers tile rows [32*wid, 32*wid+32)
  int wrow = wid * 32;
  int lrow = lane >> 2;            // 0..15
  int lcol = (lane & 3) * 8;       // elem col, 16 B chunks
  const ushort_t* gA = A + (m0 + wrow + lrow)*K + lcol;
  const ushort_t* gB = W + (size_t)(n0 + wrow + lrow)*K + lcol;
  ushort_t* lA0 = As + wrow*32;          // wave-uniform LDS bases
  ushort_t* lA1 = As + (wrow+16)*32;
  ushort_t* lB0 = Bs + wrow*32;
  ushort_t* lB1 = Bs + (wrow+16)*32;
  const size_t gs = (size_t)16*K;

  int quad = lane >> 4, r = lane & 15;

  for (int k0 = 0; k0 < K; k0 += 32){
    __syncthreads();                 // prev iter's LDS reads done
    async16(gA,      lA0);
    async16(gA + gs, lA1);
    async16(gB,      lB0);
    async16(gB + gs, lB1);
    gA += 32; gB += 32;
    __syncthreads();                 // staging drained (vmcnt0 before barrier)
    short8 af[4], bf[4];
    #pragma unroll
    for (int i = 0; i < 4; ++i) af[i] = *(const short8*)(As + (wm*64 + i*16 + r)*32 + quad*8);
    #pragma unroll
    for (int j = 0; j < 4; ++j) bf[j] = *(const short8*)(Bs + (wn*64 + j*16 + r)*32 + quad*8);
    #pragma unroll
    for (int i = 0; i < 4; ++i)
      #pragma unroll
      for (int j = 0; j < 4; ++j)
        acc[i][j] = __builtin_amdgcn_mfma_f32_16x16x32_bf16(af[i], bf[j], acc[i][j], 0, 0, 0);
  }

  int cn = lane & 15;
  #pragma unroll
  for (int i = 0; i < 4; ++i){
    #pragma unroll
    for (int j = 0; j < 4; ++j){
      int gcol = n0 + wn*64 + j*16 + cn;
      float bv = bias[gcol];
      #pragma unroll
      for (int rg = 0; rg < 4; ++rg){
        long long grow = m0 + wm*64 + i*16 + quad*4 + rg;
        float v = acc[i][j][rg] + bv;
        if (MODE == 0){
          O[grow*N + gcol] = f2b(v);
        } else if (MODE == 1){
          float g = v / (1.0f + __expf(-1.702f*v));
          O[grow*N + gcol] = f2b(g);
        } else {
          long long idx = grow*N + gcol;
          if constexpr (RF32) ((float*)Hp)[idx] += v;
          else { ushort_t* hb = (ushort_t*)Hp; hb[idx] = f2b(b2f(hb[idx]) + v); }
        }
      }
    }
  }
}

// -------- MFMA causal attention: one block per (seq b, head h) --------
__global__ __launch_bounds__(256) void k_attn(
    const ushort_t* __restrict__ QKV, ushort_t* __restrict__ Y)
{
  __shared__ char smem[55872];
  ushort_t* Qs = (ushort_t*)smem;
  ushort_t* Ks = (ushort_t*)(smem + 11520);
  float*    Ss = (float*)smem;
  ushort_t* Vt = (ushort_t*)(smem + 25920);
  ushort_t* Ps = (ushort_t*)(smem + 39232);

  int b = blockIdx.x >> 3, h = blockIdx.x & 7;
  int tid = threadIdx.x;
  int lane = tid & 63, wid = tid >> 6;
  int quad = lane >> 4, r = lane & 15;
  const ushort_t* base = QKV + (size_t)b*CTX*1536 + h*64;

  #pragma unroll
  for (int it = 0; it < 5; ++it){
    int id = tid + it*256;            // 0..1279 = 80 rows * 16 chunks
    int t  = id >> 4;
    int d4 = (id & 15) * 4;
    ushort_t q[4], k[4], v[4];
    if (t < CTX){
      const ushort_t* rp = base + (size_t)t*1536 + d4;
      *(int2*)q = *(const int2*)(rp);
      *(int2*)k = *(const int2*)(rp + 512);
      *(int2*)v = *(const int2*)(rp + 1024);
    } else {
      q[0]=q[1]=q[2]=q[3]=0; k[0]=k[1]=k[2]=k[3]=0; v[0]=v[1]=v[2]=v[3]=0;
    }
    *(int2*)(Qs + t*72 + d4) = *(int2*)q;
    *(int2*)(Ks + t*72 + d4) = *(int2*)k;
    #pragma unroll
    for (int i = 0; i < 4; ++i) Vt[(d4+i)*104 + t] = v[i];
  }
  { // zero Vt key-columns 80..95
    int z = tid * 4;
    int d = z >> 4, c = 80 + (z & 15);
    ushort_t zz[4] = {0,0,0,0};
    *(int2*)(Vt + d*104 + c) = *(int2*)zz;
  }
  __syncthreads();

  const int TI[15] = {0,1,1,2,2,2,3,3,3,3,4,4,4,4,4};
  const int TJ[15] = {0,0,1,0,1,2,0,1,2,3,0,1,2,3,4};
  floatx4 cS[4];
  int ntile = 0;
  for (int tt = wid; tt < 15; tt += 4, ++ntile){
    int i = TI[tt], j = TJ[tt];
    floatx4 c = {0.f,0.f,0.f,0.f};
    #pragma unroll
    for (int s = 0; s < 2; ++s){
      short8 aq = *(const short8*)(Qs + (i*16 + r)*72 + s*32 + quad*8);
      short8 bk = *(const short8*)(Ks + (j*16 + r)*72 + s*32 + quad*8);
      c = __builtin_amdgcn_mfma_f32_16x16x32_bf16(aq, bk, c, 0, 0, 0);
    }
    cS[ntile] = c;
  }
  __syncthreads();

  {
    int idx = 0;
    for (int tt = wid; tt < 15; tt += 4, ++idx){
      int i = TI[tt], j = TJ[tt];
      #pragma unroll
      for (int rg = 0; rg < 4; ++rg){
        int q  = i*16 + quad*4 + rg;
        int kk = j*16 + r;
        float s = cS[idx][rg] * 0.125f;
        if (kk > q) s = -1e30f;
        Ss[q*81 + kk] = s;
      }
    }
  }
  __syncthreads();

  for (int q = wid; q < 80; q += 4){
    if (q >= CTX){
      Ps[q*104 + lane] = 0;
      if (lane < 32) Ps[q*104 + 64 + lane] = 0;
      continue;
    }
    int k1 = 64 + lane;
    float s0 = (lane <= q) ? Ss[q*81 + lane] : -1e30f;
    float s1 = (k1  <= q) ? Ss[q*81 + k1 ]  : -1e30f;
    float mx = wmax(fmaxf(s0, s1));
    float e0 = (lane <= q) ? __expf(s0 - mx) : 0.0f;
    float e1 = (k1  <= q) ? __expf(s1 - mx) : 0.0f;
    float inv = 1.0f / wsum(e0 + e1);
    Ps[q*104 + lane] = f2b(e0 * inv);
    if (lane < 32) Ps[q*104 + 64 + lane] = f2b(e1 * inv);
  }
  __syncthreads();

  for (int tt = wid; tt < 20; tt += 4){
    int mi = tt >> 2, ni = tt & 3;
    floatx4 c = {0.f,0.f,0.f,0.f};
    #pragma unroll
    for (int kc = 0; kc < 3; ++kc){
      short8 ap = *(const short8*)(Ps + (mi*16 + r)*104 + kc*32 + quad*8);
      short8 bv = *(const short8*)(Vt + (ni*16 + r)*104 + kc*32 + quad*8);
      c = __builtin_amdgcn_mfma_f32_16x16x32_bf16(ap, bv, c, 0, 0, 0);
    }
    #pragma unroll
    for (int rg = 0; rg < 4; ++rg){
      int q = mi*16 + quad*4 + rg;
      if (q < CTX)
        Y[((size_t)b*CTX + q)*WIDTH + h*64 + ni*16 + r] = f2b(c[rg]);
    }
  }
}

// -------- gather EOT+LP-1 rows, final LN -> FI (bf16 [1024,512]) --------
template<bool RF32>
__global__ __launch_bounds__(256) void k_lnf_gather(
    const void* __restrict__ Hp, const int* __restrict__ posy,
    const float* __restrict__ w, const float* __restrict__ b,
    ushort_t* __restrict__ FI)
{
  int wid = threadIdx.x >> 6, lane = threadIdx.x & 63;
  int rr = blockIdx.x * 4 + wid;
  if (rr >= BSEQ) return;
  int n = rr % NTXT;
  int tok = posy[n] + LPROMPT - 1;
  long long row = (long long)rr*CTX + tok;
  float v[8];
  if constexpr (RF32){
    const float* x = (const float*)Hp + row * WIDTH;
    #pragma unroll
    for (int i = 0; i < 8; ++i) v[i] = x[lane*8 + i];
  } else {
    const ushort_t* x = (const ushort_t*)Hp + row * WIDTH;
    int4 raw = *(const int4*)(x + lane*8);
    ushort_t* u = (ushort_t*)&raw;
    #pragma unroll
    for (int i = 0; i < 8; ++i) v[i] = b2f(u[i]);
  }
  float s = 0.f, ss = 0.f;
  #pragma unroll
  for (int i = 0; i < 8; ++i){ s += v[i]; ss += v[i]*v[i]; }
  s = wsum(s); ss = wsum(ss);
  float mean = s * (1.0f/WIDTH);
  float var  = ss * (1.0f/WIDTH) - mean*mean;
  float rs = rsqrtf(var + 1e-5f);
  ushort_t o[8];
  #pragma unroll
  for (int i = 0; i < 8; ++i){
    int d = lane*8 + i;
    o[i] = f2b((v[i]-mean)*rs*w[d] + b[d]);
  }
  *(int4*)(FI + (long long)rr*WIDTH + lane*8) = *(int4*)o;
}

// -------- final projection: F[1024,1024] = FI[1024,512](bf16) @ TP[512,1024](fp32) --------
__global__ __launch_bounds__(256) void k_fproj(
    const ushort_t* __restrict__ FI, const float* __restrict__ TP,
    float* __restrict__ F)
{
  int idx = blockIdx.x * 256 + threadIdx.x;
  int e = idx & (EMBED-1);
  int m = idx >> 10;
  float acc = 0.f;
  #pragma unroll 8
  for (int k = 0; k < WIDTH; ++k)
    acc += b2f(FI[m*WIDTH + k]) * TP[k*EMBED + e];
  F[idx] = acc;
}

// -------- per-row L2 normalize in place --------
__global__ __launch_bounds__(256) void k_rownorm(float* __restrict__ F)
{
  __shared__ float red[4];
  int rr = blockIdx.x;
  float* x = F + (long long)rr*EMBED;
  float ss = 0.f;
  for (int i = threadIdx.x; i < EMBED; i += 256){ float v = x[i]; ss += v*v; }
  ss = wsum(ss);
  int wid = threadIdx.x >> 6, lane = threadIdx.x & 63;
  if (lane == 0) red[wid] = ss;
  __syncthreads();
  float inv = rsqrtf(red[0]+red[1]+red[2]+red[3]);
  for (int i = threadIdx.x; i < EMBED; i += 256) x[i] *= inv;
}

// -------- mean over n, normalize, write fp32 out --------
__global__ __launch_bounds__(256) void k_meannorm(
    const float* __restrict__ F, float* __restrict__ OUT)
{
  __shared__ float red[4];
  int p = blockIdx.x;
  float m[4]; float ss = 0.f;
  #pragma unroll
  for (int j = 0; j < 4; ++j){
    int e = threadIdx.x + j*256;
    float s = 0.f;
    for (int n = 0; n < NTXT; ++n) s += F[((long long)(p*NTXT + n))*EMBED + e];
    s *= (1.0f/NTXT);
    m[j] = s; ss += s*s;
  }
  ss = wsum(ss);
  int wid = threadIdx.x >> 6, lane = threadIdx.x & 63;
  if (lane == 0) red[wid] = ss;
  __syncthreads();
  float inv = rsqrtf(red[0]+red[1]+red[2]+red[3]);
  #pragma unroll
  for (int j = 0; j < 4; ++j)
    OUT[p*EMBED + threadIdx.x + j*256] = m[j]*inv;
}

// ============================ launcher ============================

template<bool RF32>
static void run_all(const int* text, const float* cprompt, const float* tok_emb,
                    const float* pos_emb,
                    const ushort_t* Wqkv, const float* qkv_b,
                    const ushort_t* Wout, const float* out_b,
                    const float* ln1_w, const float* ln1_b,
                    const float* ln2_w, const float* ln2_b,
                    const ushort_t* Wfc, const float* fc_b,
                    const ushort_t* Wproj, const float* proj_b,
                    const float* lnf_w, const float* lnf_b, const float* tproj,
                    int* posy, void* H, ushort_t* Y, ushort_t* BIG,
                    ushort_t* FI, float* F, float* OUT, int sc, hipStream_t stream)
{
  const int rows_c = ROWS / sc;       // multiple of 128 for sc in {1,2,4,8}
  const int seqs_c = BSEQ / sc;

  k_posy<<<1, 128, 0, stream>>>(text, posy);
  k_embed<RF32><<<(ROWS*512)/256, 256, 0, stream>>>(text, cprompt, tok_emb, pos_emb, posy, H);

  for (int L = 0; L < LAYERS; ++L){
    k_ln<RF32><<<ROWS/4, 256, 0, stream>>>(H, ln1_w + L*WIDTH, ln1_b + L*WIDTH, Y, ROWS);
    for (int c = 0; c < sc; ++c){
      size_t r0 = (size_t)c * rows_c;
      k_gemm<0,RF32><<<dim3(12, rows_c/128), 256, 0, stream>>>(
          Y + r0*WIDTH, Wqkv + (size_t)L*1536*512, qkv_b + L*1536,
          nullptr, BIG, 512, 1536);
      k_attn<<<seqs_c*HEADS, 256, 0, stream>>>(BIG, Y + r0*WIDTH);
    }
    k_gemm<2,RF32><<<dim3(4, ROWS/128), 256, 0, stream>>>(
        Y, Wout + (size_t)L*512*512, out_b + L*512, H, nullptr, 512, 512);
    k_ln<RF32><<<ROWS/4, 256, 0, stream>>>(H, ln2_w + L*WIDTH, ln2_b + L*WIDTH, Y, ROWS);
    for (int c = 0; c < sc; ++c){
      size_t r0 = (size_t)c * rows_c;
      void* Hoff = RF32 ? (void*)((float*)H + r0*WIDTH) : (void*)((ushort_t*)H + r0*WIDTH);
      k_gemm<1,RF32><<<dim3(16, rows_c/128), 256, 0, stream>>>(
          Y + r0*WIDTH, Wfc + (size_t)L*2048*512, fc_b + L*2048,
          nullptr, BIG, 512, 2048);
      k_gemm<2,RF32><<<dim3(4, rows_c/128), 256, 0, stream>>>(
          BIG, Wproj + (size_t)L*512*2048, proj_b + L*512, Hoff, nullptr, 2048, 512);
    }
  }

  k_lnf_gather<RF32><<<BSEQ/4, 256, 0, stream>>>(H, posy, lnf_w, lnf_b, FI);
  k_fproj<<<(BSEQ*EMBED)/256, 256, 0, stream>>>(FI, tproj, F);
  k_rownorm<<<BSEQ, 256, 0, stream>>>(F);
  k_meannorm<<<PP, 256, 0, stream>>>(F, OUT);
}

extern "C" void kernel_launch(void* const* d_in, const int* in_sizes, int n_in,
                              void* d_out, int out_size, void* d_ws, size_t ws_size,
                              hipStream_t stream)
{
  const int*   text    = (const int*)d_in[0];
  const float* cprompt = (const float*)d_in[1];
  const float* tok_emb = (const float*)d_in[2];
  const float* pos_emb = (const float*)d_in[3];
  const float* qkv_w   = (const float*)d_in[4];
  const float* qkv_b   = (const float*)d_in[5];
  const float* out_w   = (const float*)d_in[6];
  const float* out_b   = (const float*)d_in[7];
  const float* ln1_w   = (const float*)d_in[8];
  const float* ln1_b   = (const float*)d_in[9];
  const float* ln2_w   = (const float*)d_in[10];
  const float* ln2_b   = (const float*)d_in[11];
  const float* fc_w    = (const float*)d_in[12];
  const float* fc_b    = (const float*)d_in[13];
  const float* proj_w  = (const float*)d_in[14];
  const float* proj_b  = (const float*)d_in[15];
  const float* lnf_w   = (const float*)d_in[16];
  const float* lnf_b   = (const float*)d_in[17];
  const float* tproj   = (const float*)d_in[18];

  const size_t nQKV = (size_t)LAYERS*1536*512;
  const size_t nOUT = (size_t)LAYERS*512*512;
  const size_t nFC  = (size_t)LAYERS*2048*512;
  const size_t nPRJ = (size_t)LAYERS*512*2048;
  const size_t nWB  = nQKV + nOUT + nFC + nPRJ;

  auto al = [](size_t b){ return (b + 255) & ~(size_t)255; };
  const size_t fixed = al(NTXT*sizeof(int)) + al((size_t)ROWS*WIDTH*2 /*Y*/)
                     + al((size_t)BSEQ*WIDTH*2 /*FI*/) + al((size_t)BSEQ*EMBED*4 /*F*/)
                     + al(nWB*2);
  int sc = 8; bool hf32 = false;
  const int scs[4] = {1, 2, 4, 8};
  bool found = false;
  for (int pass = 0; pass < 2 && !found; ++pass){
    size_t hbytes = (size_t)ROWS*WIDTH*(pass == 0 ? 4 : 2);
    for (int i = 0; i < 4; ++i){
      size_t big = (size_t)(ROWS/scs[i]) * 2048 * 2;
      if (fixed + al(hbytes) + al(big) <= ws_size){
        sc = scs[i]; hf32 = (pass == 0); found = true; break;
      }
    }
  }

  char* ws = (char*)d_ws;
  size_t off = 0;
  auto alloc = [&](size_t bytes)->char*{
    char* pp = ws + off; off += (bytes + 255) & ~(size_t)255; return pp;
  };
  int*      posy = (int*)     alloc(NTXT*sizeof(int));
  void*     H    = (void*)    alloc((size_t)ROWS*WIDTH*(hf32 ? 4 : 2));
  ushort_t* Y    = (ushort_t*)alloc((size_t)ROWS*WIDTH*2);
  ushort_t* BIG  = (ushort_t*)alloc((size_t)(ROWS/sc)*2048*2);
  ushort_t* FI   = (ushort_t*)alloc((size_t)BSEQ*WIDTH*2);
  float*    F    = (float*)   alloc((size_t)BSEQ*EMBED*4);
  ushort_t* WB   = (ushort_t*)alloc(nWB*2);
  ushort_t* Wqkv = WB;
  ushort_t* Wout = WB + nQKV;
  ushort_t* Wfc  = WB + nQKV + nOUT;
  ushort_t* Wprj = WB + nQKV + nOUT + nFC;

  k_conv<<<(int)((nQKV/4 + 255)/256), 256, 0, stream>>>(qkv_w,  Wqkv, (int)(nQKV/4));
  k_conv<<<(int)((nOUT/4 + 255)/256), 256, 0, stream>>>(out_w,  Wout, (int)(nOUT/4));
  k_conv<<<(int)((nFC /4 + 255)/256), 256, 0, stream>>>(fc_w,   Wfc,  (int)(nFC /4));
  k_conv<<<(int)((nPRJ/4 + 255)/256), 256, 0, stream>>>(proj_w, Wprj, (int)(nPRJ/4));

  if (hf32)
    run_all<true >(text, cprompt, tok_emb, pos_emb, Wqkv, qkv_b, Wout, out_b,
                   ln1_w, ln1_b, ln2_w, ln2_b, Wfc, fc_b, Wprj, proj_b,
                   lnf_w, lnf_b, tproj, posy, H, Y, BIG, FI, F,
                   (float*)d_out, sc, stream);
  else
    run_all<false>(text, cprompt, tok_emb, pos_emb, Wqkv, qkv_b, Wout, out_b,
                   ln1_w, ln1_b, ln2_w, ln2_b, Wfc, fc_b, Wprj, proj_b,
                   lnf_w, lnf_b, tproj, posy, H, Y, BIG, FI, F,
                   (float*)d_out, sc, stream);
}